// Round 3
// baseline (2100.761 us; speedup 1.0000x reference)
//
#include <hip/hip_runtime.h>

typedef _Float16 half2_t __attribute__((ext_vector_type(2)));

#define BB 16
#define TT 4096
#define DD 128
#define HH 256

__device__ __forceinline__ float tanh_fast(float x) {
    // tanh(x) = 1 - 2/(exp(2x)+1); exact at both saturations
    float e = __expf(2.0f * x);
    return 1.0f - 2.0f * __builtin_amdgcn_rcpf(e + 1.0f);
}

// cross-lane helpers: xor1/xor2 via DPP quad_perm (VALU pipe), xor4 via ds_swizzle
__device__ __forceinline__ float dpp_xor1(float a) {
    return __builtin_bit_cast(float, __builtin_amdgcn_mov_dpp(
        __builtin_bit_cast(int, a), 0xB1, 0xF, 0xF, true));  // quad_perm [1,0,3,2]
}
__device__ __forceinline__ float dpp_xor2(float a) {
    return __builtin_bit_cast(float, __builtin_amdgcn_mov_dpp(
        __builtin_bit_cast(int, a), 0x4E, 0xF, 0xF, true));  // quad_perm [2,3,0,1]
}
__device__ __forceinline__ float swz_xor4(float a) {
    return __builtin_bit_cast(float, __builtin_amdgcn_ds_swizzle(
        __builtin_bit_cast(int, a), 0x101F));                // lane ^= 4
}

// ---------------- Phase 1: xh[b,t,h] = sum_d X[b,t,d]*W_x[h,d] + b_x[h] -----
__global__ __launch_bounds__(256) void x2h_gemm(
    const float* __restrict__ inp, const float* __restrict__ Wx,
    const float* __restrict__ bx, float* __restrict__ out)
{
    const int tid = threadIdx.x;
    const int ty = tid >> 4, tx = tid & 15;
    const int row0 = blockIdx.x * 128 + ty * 8;   // flattened (b,t)
    const int col0 = blockIdx.y * 128 + tx * 8;   // h

    float acc[8][8] = {};

    #pragma unroll 2
    for (int k4 = 0; k4 < DD / 4; ++k4) {
        float4 a[8], b[8];
        #pragma unroll
        for (int r = 0; r < 8; ++r)
            a[r] = *(const float4*)&inp[(size_t)(row0 + r) * DD + k4 * 4];
        #pragma unroll
        for (int c = 0; c < 8; ++c)
            b[c] = *(const float4*)&Wx[(size_t)(col0 + c) * DD + k4 * 4];
        #pragma unroll
        for (int r = 0; r < 8; ++r)
            #pragma unroll
            for (int c = 0; c < 8; ++c)
                acc[r][c] += a[r].x * b[c].x + a[r].y * b[c].y
                           + a[r].z * b[c].z + a[r].w * b[c].w;
    }

    float4 bx0 = *(const float4*)&bx[col0];
    float4 bx1 = *(const float4*)&bx[col0 + 4];
    #pragma unroll
    for (int r = 0; r < 8; ++r) {
        float4 o0, o1;
        o0.x = acc[r][0] + bx0.x; o0.y = acc[r][1] + bx0.y;
        o0.z = acc[r][2] + bx0.z; o0.w = acc[r][3] + bx0.w;
        o1.x = acc[r][4] + bx1.x; o1.y = acc[r][5] + bx1.y;
        o1.z = acc[r][6] + bx1.z; o1.w = acc[r][7] + bx1.w;
        *(float4*)&out[(size_t)(row0 + r) * HH + col0]     = o0;
        *(float4*)&out[(size_t)(row0 + r) * HH + col0 + 4] = o1;
    }
}

// ---------------- Phase 2: sequential scan, one workgroup per batch ---------
// S=8 outputs/lane, C=32 K-chunk: lane l (o=l>>3, r=l&7) computes partials for
// outputs {o+32s, s=0..7} over h[32r..32r+32). LDS traffic: 16 KB/step (was 32).
// Reads derotated (sub-slot (q+r)&3 first; weights PRE-ROTATED in registers so
// all register indices stay compile-time) -> only 2-way bank aliasing (free).
// 8-way reduction: select-exchange butterfly, xor1/xor2 via DPP quad_perm,
// xor4 via ds_swizzle. Lane finalizes output jf = o + 32r.
__global__ __launch_bounds__(256, 1) void rnn_scan(
    const float* __restrict__ Wh, const float* __restrict__ bh,
    float* __restrict__ out)
{
    const int l = threadIdx.x;          // 0..255
    const int o = l >> 3;               // 0..31  output base
    const int r = l & 7;                // 0..7   K-chunk
    const int b = blockIdx.x;           // batch
    const int jf = o + (r << 5);        // finalized output unit

    __shared__ __align__(16) _Float16 hA[HH];
    __shared__ __align__(16) _Float16 hB[HH];

    // derotated LDS byte offsets: chunk base r*64B, sub-slot (q+r)&3
    int ldoff[4];
    #pragma unroll
    for (int q = 0; q < 4; ++q)
        ldoff[q] = ((r << 2) + ((q + r) & 3)) << 4;

    // weights pre-rotated to match read order: w[s][q*4+m] covers logical
    // cols 32r + ((q+r)&3)*8 + {2m,2m+1} of row o+32s
    half2_t w[8][16];
    #pragma unroll
    for (int s = 0; s < 8; ++s) {
        const float* wr = Wh + (size_t)(o + (s << 5)) * HH + (r << 5);
        #pragma unroll
        for (int q = 0; q < 4; ++q) {
            int qq = (q + r) & 3;
            float4 v0 = *(const float4*)(wr + qq * 8);
            float4 v1 = *(const float4*)(wr + qq * 8 + 4);
            w[s][q * 4 + 0] = half2_t{(_Float16)v0.x, (_Float16)v0.y};
            w[s][q * 4 + 1] = half2_t{(_Float16)v0.z, (_Float16)v0.w};
            w[s][q * 4 + 2] = half2_t{(_Float16)v1.x, (_Float16)v1.y};
            w[s][q * 4 + 3] = half2_t{(_Float16)v1.z, (_Float16)v1.w};
        }
    }
    const float bhv = bh[jf];
    hA[l] = (_Float16)0.f;              // l spans all 256 units

    float* colp = out + (size_t)b * TT * HH + jf;   // xh column jf, stride HH

    constexpr int CH = 16;                          // prefetch chunk (timesteps)
    float xc[CH], xn[CH];
    #pragma unroll
    for (int i = 0; i < CH; ++i) xc[i] = colp[(size_t)i * HH];
    __syncthreads();   // hA (zeros) visible

    const bool s1 = (r & 1) != 0, s2 = (r & 2) != 0, s3 = (r & 4) != 0;

#define QBLK(HV, QI)                                                           \
    {                                                                          \
        half2_t h0 = __builtin_bit_cast(half2_t, (HV).x);                      \
        half2_t h1 = __builtin_bit_cast(half2_t, (HV).y);                      \
        half2_t h2 = __builtin_bit_cast(half2_t, (HV).z);                      \
        half2_t h3 = __builtin_bit_cast(half2_t, (HV).w);                      \
        _Pragma("unroll")                                                      \
        for (int s = 0; s < 8; ++s) {                                          \
            a[s] = __builtin_amdgcn_fdot2(h0, w[s][(QI) * 4 + 0], a[s], false);\
            a[s] = __builtin_amdgcn_fdot2(h1, w[s][(QI) * 4 + 1], a[s], false);\
            a[s] = __builtin_amdgcn_fdot2(h2, w[s][(QI) * 4 + 2], a[s], false);\
            a[s] = __builtin_amdgcn_fdot2(h3, w[s][(QI) * 4 + 3], a[s], false);\
        }                                                                      \
    }

#define DOT_STEP(SRC, DST, XV, OPTR)                                           \
    {                                                                          \
        const char* hbase = (const char*)(SRC);                                \
        uint4 hv0 = *(const uint4*)(hbase + ldoff[0]);                         \
        uint4 hv1 = *(const uint4*)(hbase + ldoff[1]);                         \
        uint4 hv2 = *(const uint4*)(hbase + ldoff[2]);                         \
        uint4 hv3 = *(const uint4*)(hbase + ldoff[3]);                         \
        float a[8] = {};                                                       \
        QBLK(hv0, 0) QBLK(hv1, 1) QBLK(hv2, 2) QBLK(hv3, 3)                    \
        /* stage 1: xor1 — keep s with s&1==r&1 */                             \
        float b0, b1, b2, b3, tk, ts;                                          \
        tk = s1 ? a[1] : a[0]; ts = s1 ? a[0] : a[1]; b0 = tk + dpp_xor1(ts);  \
        tk = s1 ? a[3] : a[2]; ts = s1 ? a[2] : a[3]; b1 = tk + dpp_xor1(ts);  \
        tk = s1 ? a[5] : a[4]; ts = s1 ? a[4] : a[5]; b2 = tk + dpp_xor1(ts);  \
        tk = s1 ? a[7] : a[6]; ts = s1 ? a[6] : a[7]; b3 = tk + dpp_xor1(ts);  \
        /* stage 2: xor2 — keep s with s&2==r&2 */                             \
        float c0, c1;                                                          \
        tk = s2 ? b1 : b0; ts = s2 ? b0 : b1; c0 = tk + dpp_xor2(ts);          \
        tk = s2 ? b3 : b2; ts = s2 ? b2 : b3; c1 = tk + dpp_xor2(ts);          \
        /* stage 3: xor4 — keep s == r */                                      \
        tk = s3 ? c1 : c0; ts = s3 ? c0 : c1;                                  \
        float av = tk + swz_xor4(ts);                                          \
        float z  = (XV) + bhv + av;                                            \
        float hn = tanh_fast(z);                                               \
        *(OPTR) = hn;                                                          \
        (DST)[jf] = (_Float16)hn;                                              \
    }                                                                          \
    __syncthreads();

    const int NC = TT / CH;
    for (int c = 0; c < NC; ++c) {
        if (c + 1 < NC) {
            const float* p = colp + (size_t)(c + 1) * CH * HH;
            #pragma unroll
            for (int i = 0; i < CH; ++i) xn[i] = p[(size_t)i * HH];
        }
        float* op = colp + (size_t)c * CH * HH;
        #pragma unroll
        for (int s = 0; s < CH; s += 2) {
            DOT_STEP(hA, hB, xc[s],     op + (size_t)s * HH)
            DOT_STEP(hB, hA, xc[s + 1], op + (size_t)(s + 1) * HH)
        }
        #pragma unroll
        for (int i = 0; i < CH; ++i) xc[i] = xn[i];
    }
#undef DOT_STEP
#undef QBLK
}

extern "C" void kernel_launch(void* const* d_in, const int* in_sizes, int n_in,
                              void* d_out, int out_size, void* d_ws, size_t ws_size,
                              hipStream_t stream) {
    const float* inp = (const float*)d_in[0];   // [B,T,D]
    const float* Wx  = (const float*)d_in[1];   // [H,D]
    const float* bx  = (const float*)d_in[2];   // [H]
    const float* Wh  = (const float*)d_in[3];   // [H,H]
    const float* bh  = (const float*)d_in[4];   // [H]
    float* out = (float*)d_out;                 // [B,T,H]

    dim3 g1(BB * TT / 128, HH / 128);
    x2h_gemm<<<g1, 256, 0, stream>>>(inp, Wx, bx, out);
    rnn_scan<<<BB, 256, 0, stream>>>(Wh, bh, out);
}